// Round 2
// baseline (492.961 us; speedup 1.0000x reference)
//
#include <hip/hip_runtime.h>

// Problem constants
#define N_PTS   65536      // B*H*W = 64*32*32
#define K_CODES 1024
#define C_DIM   64
#define HW      1024       // H*W
#define Q_ELEMS 4194304    // 64*64*32*32

// d_out layout (float32): [vq_loss(1) | quantized(4194304) | perplexity(1) | indices(65536)]
#define OUT_Q_OFF 1
#define OUT_P_OFF 4194305
#define OUT_I_OFF 4194306

// ws layout (bytes)
#define WS_CSUM 0          // 1024 float  B_k = sum(c^2)        (4096 B)
#define WS_IDX  4096       // 65536 int                          (262144 B)
#define WS_HIST 266240     // 1024 u32                           (4096 B)
#define WS_SSE  270336     // 1 double                           (8 B)

// numpy pairwise sum (n=64, contiguous, blocksize<=128 path):
// 8 accumulators striding by 8, then ((r0+r1)+(r2+r3))+((r4+r5)+(r6+r7)).
// All roundings explicit f32 (no contraction).
__device__ __forceinline__ float np_pairwise_sumsq64(const float* __restrict__ a) {
    float r[8];
    #pragma unroll
    for (int j = 0; j < 8; ++j) r[j] = __fmul_rn(a[j], a[j]);
    #pragma unroll
    for (int i = 8; i < 64; i += 8) {
        #pragma unroll
        for (int j = 0; j < 8; ++j)
            r[j] = __fadd_rn(r[j], __fmul_rn(a[i + j], a[i + j]));
    }
    return __fadd_rn(__fadd_rn(__fadd_rn(r[0], r[1]), __fadd_rn(r[2], r[3])),
                     __fadd_rn(__fadd_rn(r[4], r[5]), __fadd_rn(r[6], r[7])));
}

// Prep: B_k = pairwise-f32 sum of codebook row squares.
__global__ void vq_prep(const float* __restrict__ cb, float* __restrict__ csum) {
    int k = blockIdx.x * blockDim.x + threadIdx.x;
    if (k < K_CODES) csum[k] = np_pairwise_sumsq64(cb + k * C_DIM);
}

// Main: per-point argmin replicating the reference's f32 rounding:
//   dist = fl32( fl32(A_n + B_k) - fl32(2 * seqFMA_d(x_d * c_kd)) )
// One thread per point; x in registers; codebook rows wave-uniform -> s_load.
__global__ __launch_bounds__(256, 1) void vq_main(
        const float* __restrict__ latents,
        const float* __restrict__ cb,
        const float* __restrict__ csum,
        int* __restrict__ idx_ws,
        unsigned int* __restrict__ hist,
        double* __restrict__ sse,
        float* __restrict__ out) {
    int n  = blockIdx.x * 256 + threadIdx.x;   // point id; grid covers N exactly
    int b  = n >> 10;
    int hw = n & 1023;

    // x_flat[n][d] = latents[b][d][hw]; coalesced across lanes
    const float* xb = latents + (size_t)b * C_DIM * HW + hw;
    float x[C_DIM];
    #pragma unroll
    for (int d = 0; d < C_DIM; ++d) x[d] = xb[(size_t)d * HW];

    const float A = np_pairwise_sumsq64(x);

    float best = 3.0e38f;
    int bidx = 0;
    for (int k = 0; k < K_CODES; ++k) {
        const float* cbk = cb + (k << 6);      // uniform address -> scalar loads
        // sequential ascending-d FMA chain (BLAS/Eigen/Tensile inner product order)
        float m = 0.0f;
        #pragma unroll
        for (int d = 0; d < C_DIM; ++d) m = __fmaf_rn(x[d], cbk[d], m);
        float dist = __fsub_rn(__fadd_rn(A, csum[k]), __fmul_rn(2.0f, m));
        bool lt = dist < best;                 // strict < : first-min tie-break
        bidx = lt ? k : bidx;
        best = lt ? dist : best;
    }

    idx_ws[n] = bidx;
    out[OUT_I_OFF + n] = (float)bidx;
    atomicAdd(&hist[bidx], 1u);

    // SSE contribution in f64 (loss threshold is lenient; f64 is plenty)
    const float* cq = cb + (bidx << 6);
    double e = 0.0;
    #pragma unroll
    for (int d = 0; d < C_DIM; ++d) {
        double df = (double)x[d] - (double)cq[d];
        e = fma(df, df, e);
    }
    #pragma unroll
    for (int off = 32; off > 0; off >>= 1) e += __shfl_down(e, off, 64);
    if ((threadIdx.x & 63) == 0) atomicAdd(sse, e);
}

// Quantized output in [B,C,H,W]: out[t] = codebook[idx[b,hw]][c]
__global__ void vq_scatter(const float* __restrict__ cb,
                           const int* __restrict__ idx_ws,
                           float* __restrict__ out) {
    int t  = blockIdx.x * 256 + threadIdx.x;   // grid covers Q_ELEMS exactly
    int b  = t >> 16;
    int c  = (t >> 10) & 63;
    int hw = t & 1023;
    int k  = idx_ws[(b << 10) | hw];
    out[OUT_Q_OFF + t] = cb[k * C_DIM + c];
}

// Finalize: perplexity from histogram, vq_loss from SSE.
__global__ void vq_final(const unsigned int* __restrict__ hist,
                         const double* __restrict__ sse,
                         float* __restrict__ out) {
    __shared__ double red[256];
    int t = threadIdx.x;
    double s = 0.0;
    for (int i = t; i < K_CODES; i += 256) {
        double p = (double)hist[i] / (double)N_PTS;
        s += p * log(p + 1e-10);
    }
    red[t] = s;
    __syncthreads();
    for (int w = 128; w > 0; w >>= 1) {
        if (t < w) red[t] += red[t + w];
        __syncthreads();
    }
    if (t == 0) {
        out[OUT_P_OFF] = (float)exp(-red[0]);
        out[0] = (float)(1.25 * sse[0] / (double)Q_ELEMS);
    }
}

extern "C" void kernel_launch(void* const* d_in, const int* in_sizes, int n_in,
                              void* d_out, int out_size, void* d_ws, size_t ws_size,
                              hipStream_t stream) {
    const float* latents = (const float*)d_in[0];
    const float* cb      = (const float*)d_in[1];
    float* out = (float*)d_out;
    char* ws = (char*)d_ws;

    float*        csum   = (float*)(ws + WS_CSUM);
    int*          idx_ws = (int*)(ws + WS_IDX);
    unsigned int* hist   = (unsigned int*)(ws + WS_HIST);
    double*       sse    = (double*)(ws + WS_SSE);

    // zero histogram + sse accumulator (contiguous)
    hipMemsetAsync(ws + WS_HIST, 0, 4096 + 8, stream);

    vq_prep   <<<4, 256, 0, stream>>>(cb, csum);
    vq_main   <<<N_PTS / 256, 256, 0, stream>>>(latents, cb, csum, idx_ws, hist, sse, out);
    vq_scatter<<<Q_ELEMS / 256, 256, 0, stream>>>(cb, idx_ws, out);
    vq_final  <<<1, 256, 0, stream>>>(hist, sse, out);
}